// Round 4
// baseline (150.941 us; speedup 1.0000x reference)
//
#include <hip/hip_runtime.h>
#include <math.h>

// Problem constants
#define NIMG 512          // B*C = 64*8
#define HH   256          // H
#define MM   32           // M (kept modes per axis)
#define EPSF 1e-8f
#define PAD2 18           // padded k1-stride (float2 units) for T2, 16B-aligned rows

// d_out float offsets (outputs concatenated flat in reference return order)
#define O0 0u             // modal_energies        [512][32][32]
#define O1 524288u        // modal_uncertainties   [512][32][32]
#define O2 1048576u       // energy_fractions      [512][32][32]
#define O3 1572864u       // weighted_importance   [512][32][32]
#define O4 2097152u       // uncertainty_spectrum  [32][32]
#define O5 2098176u       // energy_spectrum       [32][32]
#define O6 2099200u       // modal_errors          [512][32][32]
#define O7 2623488u       // calibration_scores    [32][32]

// d_ws float offsets
#define TW_OFF  0                            // 256 x (cos,sin) = 512 floats
#define PM_OFF  512                          // pred modes [512][32][32][2]
#define GM_OFF  (512 + NIMG*MM*MM*2)         // gt modes
#define TOT_OFF (512 + 2*NIMG*MM*MM*2)       // per-image total energy [512]

// ---------------------------------------------------------------------------
// Twiddle table: tw[t] = (cos(2*pi*t/256), sin(2*pi*t/256))
__global__ void init_tw_kernel(float* __restrict__ tw) {
  int t = threadIdx.x;  // 256 threads
  double th = (2.0 * M_PI / 256.0) * (double)t;
  tw[2*t]   = (float)cos(th);
  tw[2*t+1] = (float)sin(th);
}

// ---------------------------------------------------------------------------
// Truncated 2D DFT: one block per (image, tensor). 256 threads.
// Stage 1 (DIT-8 over n1 = a + 32b): per a, constant-twiddle 8-pt real DFT
//   over b in registers, then X[8m+r] += W32^{a m} * (W256^{a r} * Z[r]).
//   Twiddles read from GLOBAL with wave-uniform indices -> s_load (scalar
//   pipe, no vector-issue cost). Input loads double-buffered across bodies.
// Stage 2 (two passes over k1-halves): radix-4 fold over n2, unroll x4 so
//   16 ds_read_b64 are in flight per body; residue r = k2 mod 4 is
//   wave-uniform; twiddle by complex recurrence.
__global__ __launch_bounds__(256, 4) void dft_kernel(
    const float* __restrict__ pred, const float* __restrict__ gt,
    const float* __restrict__ tw,
    float* __restrict__ Pm, float* __restrict__ Gm,
    float* __restrict__ tot, float* __restrict__ out_energy)
{
  __shared__ __align__(16) float2 T2[256 * PAD2];   // 36864 B
  __shared__ float red[4];                          // block energy reduction

  const int t    = threadIdx.x;
  const int img  = blockIdx.x & (NIMG - 1);
  const int isGt = blockIdx.x >> 9;
  const float* __restrict__ x =
      (isGt ? gt : pred) + (size_t)img * (HH * HH) + t;
  const float2* __restrict__ tw2g = (const float2*)tw;

  // ---- stage 1: DIT-8 ----
  float accR[32], accI[32];
#pragma unroll
  for (int k = 0; k < 32; ++k) { accR[k] = 0.f; accI[k] = 0.f; }

  auto body = [&](int aa, const float* v) {
    float v0 = v[0], v1 = v[1], v2 = v[2], v3 = v[3],
          v4 = v[4], v5 = v[5], v6 = v[6], v7 = v[7];

    // 8-point real DFT over b (W8 constants only)
    float w0 = v0 + v4, w1 = v1 + v5, w2 = v2 + v6, w3 = v3 + v7;
    float d0 = v0 - v4, d1 = v1 - v5, d2 = v2 - v6, d3 = v3 - v7;
    float A0 = w0 + w2, A1 = w0 - w2, A2 = w1 + w3, A3 = w1 - w3;
    float Z0 = A0 + A2, Z4 = A0 - A2;          // real
    float Z2r = A1, Z2i = -A3;
    const float SQ = 0.70710678118654752f;
    float pp = SQ * (d1 - d3), qq2 = SQ * (d1 + d3);
    float Z1r = d0 + pp, Z1i = -(d2 + qq2);
    float Z3r = d0 - pp, Z3i = d2 - qq2;

    // m-step twiddles W32^{aa m} = (mr, -ms), m = 1..3 (uniform -> s_load)
    float2 tm1 = tw2g[(8 * aa) & 255];
    float2 tm2 = tw2g[(16 * aa) & 255];
    float2 tm3 = tw2g[(24 * aa) & 255];
    float m1r = tm1.x, m1s = tm1.y;
    float m2r = tm2.x, m2s = tm2.y;
    float m3r = tm3.x, m3s = tm3.y;

    // X[8m+r] += (mr,-ms) * Y :  Xr += mr*Yr + ms*Yi ; Xi += mr*Yi - ms*Yr
#define ACC4(r, Yr, Yi)                                                  \
    accR[(r)]    += (Yr);  accI[(r)]    += (Yi);                         \
    accR[8+(r)]  = fmaf(m1r,(Yr), fmaf( m1s,(Yi), accR[8+(r)]));         \
    accI[8+(r)]  = fmaf(m1r,(Yi), fmaf(-m1s,(Yr), accI[8+(r)]));         \
    accR[16+(r)] = fmaf(m2r,(Yr), fmaf( m2s,(Yi), accR[16+(r)]));        \
    accI[16+(r)] = fmaf(m2r,(Yi), fmaf(-m2s,(Yr), accI[16+(r)]));        \
    accR[24+(r)] = fmaf(m3r,(Yr), fmaf( m3s,(Yi), accR[24+(r)]));        \
    accI[24+(r)] = fmaf(m3r,(Yi), fmaf(-m3s,(Yr), accI[24+(r)]));

    // r = 0 : Y = Z0 (real); X[0] stays real
    {
      accR[0] += Z0;
      accR[8]  = fmaf(m1r, Z0, accR[8]);  accI[8]  = fmaf(-m1s, Z0, accI[8]);
      accR[16] = fmaf(m2r, Z0, accR[16]); accI[16] = fmaf(-m2s, Z0, accI[16]);
      accR[24] = fmaf(m3r, Z0, accR[24]); accI[24] = fmaf(-m3s, Z0, accI[24]);
    }
    // r = 4 : Y = W256^{4aa} * Z4 (Z4 real)
    {
      float2 tt = tw2g[(4 * aa) & 255];
      float Yr = tt.x * Z4, Yi = -tt.y * Z4;
      ACC4(4, Yr, Yi)
    }
    // complex residues: Y = (tt.x, -tt.y) * (Zr, Zi)
#define CPLX_R(r, Zr, Zi)                                                \
    {                                                                    \
      float2 tt = tw2g[((r) * aa) & 255];                                \
      float Yr = fmaf(tt.x, (Zr),  tt.y * (Zi));                         \
      float Yi = fmaf(tt.x, (Zi), -tt.y * (Zr));                         \
      ACC4(r, Yr, Yi)                                                    \
    }
    CPLX_R(1, Z1r,  Z1i)
    CPLX_R(2, Z2r,  Z2i)
    CPLX_R(3, Z3r,  Z3i)
    CPLX_R(5, Z3r, -Z3i)   // Z5 = conj(Z3)
    CPLX_R(6, Z2r, -Z2i)   // Z6 = conj(Z2)
    CPLX_R(7, Z1r, -Z1i)   // Z7 = conj(Z1)
#undef CPLX_R
#undef ACC4
  };

  float vA[8], vB[8];
#pragma unroll
  for (int b = 0; b < 8; ++b) vA[b] = x[b * 8192];   // a = 0

#pragma unroll 1
  for (int a = 0; a < 32; a += 2) {
#pragma unroll
    for (int b = 0; b < 8; ++b) vB[b] = x[(a + 1) * 256 + b * 8192];
    body(a, vA);
    if (a < 30) {
#pragma unroll
      for (int b = 0; b < 8; ++b) vA[b] = x[(a + 2) * 256 + b * 8192];
    }
    body(a + 1, vB);
  }

  // ---- stage 2: two passes over k1-halves, radix-4 fold over n2 ----
  float* __restrict__ Mo = (isGt ? Gm : Pm) + (size_t)img * (MM * MM * 2);
  const int wv  = t >> 6;        // wave id = residue r (wave-uniform)
  const int l   = t & 63;
  const int k1l = l >> 2;        // 0..15
  const int qq  = l & 3;
  const int k2A = 4 * qq + wv;
  const int k2B = k2A + 16;
  float2 tA = tw2g[k2A]; const float rAx = tA.x, rAy = -tA.y;
  float2 tB = tw2g[k2B]; const float rBx = tB.x, rBy = -tB.y;
  float eacc = 0.f;

#pragma unroll 1
  for (int p = 0; p < 2; ++p) {
    __syncthreads();             // prior-pass T2 reads complete
    {
      float4* rowp = (float4*)&T2[t * PAD2];
#pragma unroll
      for (int k = 0; k < 8; ++k)
        rowp[k] = make_float4(accR[16 * p + 2 * k], accI[16 * p + 2 * k],
                              accR[16 * p + 2 * k + 1], accI[16 * p + 2 * k + 1]);
    }
    __syncthreads();

    float wAr = 1.f, wAi = 0.f, wBr = 1.f, wBi = 0.f;
    float XAr = 0.f, XAi = 0.f, XBr = 0.f, XBi = 0.f;
#pragma unroll 4
    for (int n2 = 0; n2 < 64; ++n2) {
      float2 T0 = T2[(n2      ) * PAD2 + k1l];
      float2 T1 = T2[(n2 +  64) * PAD2 + k1l];
      float2 Tc = T2[(n2 + 128) * PAD2 + k1l];
      float2 T3 = T2[(n2 + 192) * PAD2 + k1l];
      float yr, yi;
      if (wv == 0) {              // wave-uniform branch
        yr = (T0.x + Tc.x) + (T1.x + T3.x);
        yi = (T0.y + Tc.y) + (T1.y + T3.y);
      } else if (wv == 2) {
        yr = (T0.x + Tc.x) - (T1.x + T3.x);
        yi = (T0.y + Tc.y) - (T1.y + T3.y);
      } else {
        float s1r = T0.x - Tc.x, s1i = T0.y - Tc.y;
        float s3r = T1.x - T3.x, s3i = T1.y - T3.y;
        if (wv == 1) { yr = s1r + s3i; yi = s1i - s3r; }
        else         { yr = s1r - s3i; yi = s1i + s3r; }
      }
      XAr = fmaf(wAr, yr, fmaf(-wAi, yi, XAr));
      XAi = fmaf(wAr, yi, fmaf( wAi, yr, XAi));
      XBr = fmaf(wBr, yr, fmaf(-wBi, yi, XBr));
      XBi = fmaf(wBr, yi, fmaf( wBi, yr, XBi));
      float nAr = fmaf(wAr, rAx, -wAi * rAy);
      float nAi = fmaf(wAr, rAy,  wAi * rAx);
      float nBr = fmaf(wBr, rBx, -wBi * rBy);
      float nBi = fmaf(wBr, rBy,  wBi * rBx);
      wAr = nAr; wAi = nAi; wBr = nBr; wBi = nBi;
    }

    const int k1 = k1l + 16 * p;
    const int mA = k1 * MM + k2A;
    const int mB = k1 * MM + k2B;
    ((float2*)Mo)[mA] = make_float2(XAr, XAi);
    ((float2*)Mo)[mB] = make_float2(XBr, XBi);
    if (!isGt) {
      float eA = fmaf(XAr, XAr, XAi * XAi);
      float eB = fmaf(XBr, XBr, XBi * XBi);
      out_energy[(size_t)img * (MM * MM) + mA] = eA;
      out_energy[(size_t)img * (MM * MM) + mB] = eB;
      eacc += eA + eB;
    }
  }

  if (!isGt) {   // block-uniform branch
#pragma unroll
    for (int off = 32; off >= 1; off >>= 1) eacc += __shfl_down(eacc, off);
    if ((t & 63) == 0) red[t >> 6] = eacc;
    __syncthreads();
    if (t == 0) tot[img] = (red[0] + red[1]) + (red[2] + red[3]);
  }
}

// ---------------------------------------------------------------------------
// Per-mode MLP + elementwise outputs. One thread per (img, mode).
__global__ __launch_bounds__(256) void mlp_kernel(
    const float* __restrict__ Pm, const float* __restrict__ Gm,
    const float* __restrict__ tot,
    const float* __restrict__ W1, const float* __restrict__ b1,
    const float* __restrict__ W2, const float* __restrict__ b2,
    const float* __restrict__ W3, const float* __restrict__ b3,
    float* __restrict__ out)
{
  int gid = blockIdx.x * 256 + threadIdx.x;   // 0 .. 524287
  int img = gid >> 10;

  float2 pm = *(const float2*)&Pm[2 * (size_t)gid];
  float2 gm = *(const float2*)&Gm[2 * (size_t)gid];

  float er = pm.x - gm.x, ei = pm.y - gm.y;
  float merr   = fmaf(er, er, ei * ei);
  float energy = fmaf(pm.x, pm.x, pm.y * pm.y);
  float frac   = energy / (tot[img] + EPSF);

  float h1[64];
#pragma unroll
  for (int j = 0; j < 64; ++j)
    h1[j] = fmaxf(fmaf(pm.x, W1[j], fmaf(pm.y, W1[64 + j], b1[j])), 0.f);

  float h2[32];
#pragma unroll
  for (int k = 0; k < 32; ++k) h2[k] = b2[k];
#pragma unroll
  for (int j = 0; j < 64; ++j) {
#pragma unroll
    for (int k = 0; k < 32; ++k)
      h2[k] = fmaf(h1[j], W2[j * 32 + k], h2[k]);
  }
  float z = b3[0];
#pragma unroll
  for (int k = 0; k < 32; ++k) z = fmaf(fmaxf(h2[k], 0.f), W3[k], z);

  float u = fmaxf(z, 0.f) + log1pf(expf(-fabsf(z)));

  out[O0 + gid] = energy;
  out[O1 + gid] = u;
  out[O2 + gid] = frac;
  out[O3 + gid] = frac * u;
  out[O6 + gid] = merr;
}

// ---------------------------------------------------------------------------
// Per-mode reductions over the 512-image axis: spectra + Pearson correlation.
__global__ __launch_bounds__(64) void corr_kernel(float* __restrict__ out)
{
  int mode = blockIdx.x;     // 0..1023
  int lane = threadIdx.x;    // 0..63

  double su = 0.0, se = 0.0, sen = 0.0, suu = 0.0, see = 0.0, sue = 0.0;
  for (int i = lane; i < NIMG; i += 64) {
    float u  = out[O1 + (size_t)i * 1024 + mode];
    float e  = out[O6 + (size_t)i * 1024 + mode];
    float en = out[O0 + (size_t)i * 1024 + mode];
    su  += (double)u;  se  += (double)e;  sen += (double)en;
    suu += (double)u * (double)u;
    see += (double)e * (double)e;
    sue += (double)u * (double)e;
  }
#pragma unroll
  for (int off = 32; off >= 1; off >>= 1) {
    su  += __shfl_down(su,  off);
    se  += __shfl_down(se,  off);
    sen += __shfl_down(sen, off);
    suu += __shfl_down(suu, off);
    see += __shfl_down(see, off);
    sue += __shfl_down(sue, off);
  }
  if (lane == 0) {
    const double N = (double)NIMG;
    double num = sue - su * se / N;
    double du  = suu - su * su / N;
    double de  = see - se * se / N;
    double den = sqrt(du * de);
    out[O4 + mode] = (float)(su / N);
    out[O5 + mode] = (float)(sen / N);
    out[O7 + mode] = (float)(num / (den + 1e-8));
  }
}

// ---------------------------------------------------------------------------
extern "C" void kernel_launch(void* const* d_in, const int* in_sizes, int n_in,
                              void* d_out, int out_size, void* d_ws, size_t ws_size,
                              hipStream_t stream)
{
  const float* pred = (const float*)d_in[0];
  const float* gt   = (const float*)d_in[2];
  const float* W1   = (const float*)d_in[3];
  const float* b1   = (const float*)d_in[4];
  const float* W2   = (const float*)d_in[5];
  const float* b2   = (const float*)d_in[6];
  const float* W3   = (const float*)d_in[7];
  const float* b3   = (const float*)d_in[8];

  float* out = (float*)d_out;
  float* ws  = (float*)d_ws;
  float* tw  = ws + TW_OFF;
  float* Pm  = ws + PM_OFF;
  float* Gm  = ws + GM_OFF;
  float* tot = ws + TOT_OFF;

  hipLaunchKernelGGL(init_tw_kernel, dim3(1), dim3(256), 0, stream, tw);
  hipLaunchKernelGGL(dft_kernel, dim3(1024), dim3(256), 0, stream,
                     pred, gt, tw, Pm, Gm, tot, out + O0);
  hipLaunchKernelGGL(mlp_kernel, dim3(2048), dim3(256), 0, stream,
                     Pm, Gm, tot, W1, b1, W2, b2, W3, b3, out);
  hipLaunchKernelGGL(corr_kernel, dim3(1024), dim3(64), 0, stream, out);
}